// Round 9
// baseline (313.685 us; speedup 1.0000x reference)
//
#include <hip/hip_runtime.h>
#include <hip/hip_bf16.h>
#include <hip/hip_cooperative_groups.h>
#include <string.h>

namespace cg = cooperative_groups;

#define E_CNT 500000
#define N_CNT 100000
#define HID   256
#define NTILE 31250   // E/16

typedef short short8 __attribute__((ext_vector_type(8)));
typedef float f32x4 __attribute__((ext_vector_type(4)));

__device__ __forceinline__ unsigned short f2bf(float f){
  union { float f; unsigned int i; } v; v.f = f;
  unsigned int u = v.i;
  u = u + 0x7FFFu + ((u >> 16) & 1u);
  return (unsigned short)(u >> 16);
}

__device__ __forceinline__ unsigned int pk_bf16(float a, float b){
  __hip_bfloat162 p = __float22bfloat162_rn(make_float2(a, b));
  unsigned int u; memcpy(&u, &p, 4); return u;
}

// W1-augmented A-fragment staging. Row ch (24 shorts, 48 B):
// k0..7=W1[k][ch], k8..15=W1 again, k16=2*b1[ch], k17..23=0.
__device__ __forceinline__ void init_w1_lds(unsigned short* w1l,
                                            const float* W1, const float* b1,
                                            int tid){
  int ch = tid;
  #pragma unroll
  for (int j = 0; j < 8; ++j){
    unsigned short w = f2bf(W1[j * HID + ch]);
    w1l[ch * 24 + j]     = w;
    w1l[ch * 24 + 8 + j] = w;
  }
  w1l[ch * 24 + 16] = f2bf(2.0f * b1[ch]);
  #pragma unroll
  for (int j = 17; j < 24; ++j) w1l[ch * 24 + j] = 0;
  if (tid < 32) w1l[256 * 24 + tid] = 0;   // tail pad for q=3 of ch=255
}

// ===================== fused cooperative kernel =============================
// phase1 = k1 (r6-proven register-direct form), grid.sync,
// phase2 = kMid on blocks 0..63, grid.sync, phase3 = k3 (r6-proven form).
// LDS: w1l (12.4KB, all phases) + 33.8KB pool overlaid per phase -> 46.2KB
// -> 3 blocks/CU (LDS-bound).  No min-wave bound (r3/r8 lesson: reg caps
// spill); grid is set from the occupancy query so co-residency always holds.
__global__ __launch_bounds__(256) void kFused(
    const int* __restrict__ eidx, const float* __restrict__ nf,
    const float* __restrict__ ea,
    const float* __restrict__ W1, const float* __restrict__ b1,
    const float* __restrict__ gamma, const float* __restrict__ beta,
    const float* __restrict__ nW2,
    const float* __restrict__ Wv, const float* __restrict__ Wo,
    const float* __restrict__ Wp,
    const float* __restrict__ bv, const float* __restrict__ bo,
    const float* __restrict__ bp, const float* __restrict__ nb2,
    float* __restrict__ part, unsigned short* __restrict__ wd2t,
    float* __restrict__ bd2, unsigned short* __restrict__ ctxw,
    float* __restrict__ out)
{
  __shared__ unsigned short w1l[256 * 24 + 32];           // 12,352 B
  __shared__ __align__(16) unsigned char pool[33824];     // phase overlay

  const int tid = threadIdx.x, lane = tid & 63, wid = tid >> 6;
  const int m = lane & 15, q = lane >> 4;
  const f32x4 z4 = {0.f, 0.f, 0.f, 0.f};

  // ---------------- phase 1: k1 batch stats --------------------------------
  {
    float* sred = (float*)pool;    // [2][4][128]
    const int cg = wid & 1;
    const int pair = (blockIdx.x * 4 + wid) >> 1;
    const int npair = gridDim.x * 2;

    if (blockIdx.x == 0 && tid < 16) bd2[tid] = 0.f;   // phase2 atomics later

    init_w1_lds(w1l, W1, b1, tid);
    __syncthreads();

    short8 w1fr[8];
    #pragma unroll
    for (int nt = 0; nt < 8; ++nt)
      w1fr[nt] = *(const short8*)&w1l[((cg * 8 + nt) * 16 + m) * 24 + q * 8];

    f32x4 sacc[8], qacc[8];
    #pragma unroll
    for (int nt = 0; nt < 8; ++nt){ sacc[nt] = z4; qacc[nt] = z4; }

    short8 kc = {0,0,0,0,0,0,0,0};
    if (q == 2) kc[0] = (short)0x3F80;
    const bool ld = (q < 2);

    int t = pair;
    int idc = 0;
    float4 nfa = make_float4(0.f,0.f,0.f,0.f), nfb = nfa;
    if (ld){
      int id0 = eidx[q * E_CNT + t * 16 + m];
      nfa = ((const float4*)nf)[id0 * 2];
      nfb = ((const float4*)nf)[id0 * 2 + 1];
      int tn = t + npair;
      if (tn < NTILE) idc = eidx[q * E_CNT + tn * 16 + m];
    }

    for (; t < NTILE; t += npair){
      short8 bfr = kc;
      if (ld){
        union { short8 s; uint4 u; } bu;
        bu.u = make_uint4(pk_bf16(nfa.x, nfa.y), pk_bf16(nfa.z, nfa.w),
                          pk_bf16(nfb.x, nfb.y), pk_bf16(nfb.z, nfb.w));
        bfr = bu.s;
        if (cg == 0)
          *(uint4*)&ctxw[(size_t)t * 256 + q * 128 + m * 8] = bu.u;
      }

      int tn1 = t + npair, tn2 = t + 2 * npair;
      if (ld && tn1 < NTILE){
        nfa = ((const float4*)nf)[idc * 2];
        nfb = ((const float4*)nf)[idc * 2 + 1];
        if (tn2 < NTILE) idc = eidx[q * E_CNT + tn2 * 16 + m];
      }

      #pragma unroll
      for (int nt = 0; nt < 8; ++nt){
        f32x4 c = __builtin_amdgcn_mfma_f32_16x16x32_bf16(w1fr[nt], bfr, z4, 0, 0, 0);
        f32x4 hv = __builtin_elementwise_max(c, z4);
        sacc[nt] += hv;
        qacc[nt] += hv * hv;
      }
    }

    #pragma unroll
    for (int nt = 0; nt < 8; ++nt){
      #pragma unroll
      for (int i = 0; i < 4; ++i){
        float v = sacc[nt][i], w = qacc[nt][i];
        v += __shfl_xor(v, 1); w += __shfl_xor(w, 1);
        v += __shfl_xor(v, 2); w += __shfl_xor(w, 2);
        v += __shfl_xor(v, 4); w += __shfl_xor(w, 4);
        v += __shfl_xor(v, 8); w += __shfl_xor(w, 8);
        if (m == 0){
          int loc = nt * 16 + q * 4 + i;
          sred[(0 * 4 + wid) * 128 + loc] = v;
          sred[(1 * 4 + wid) * 128 + loc] = w;
        }
      }
    }
    __syncthreads();
    {
      int j = tid, hf = j >> 7, loc = j & 127;
      float s0 = sred[(0*4 + hf) * 128 + loc] + sred[(0*4 + hf + 2) * 128 + loc];
      float s1 = sred[(1*4 + hf) * 128 + loc] + sred[(1*4 + hf + 2) * 128 + loc];
      part[blockIdx.x * 512 + j]       = s0;
      part[blockIdx.x * 512 + 256 + j] = s1;
    }
  }

  cg::this_grid().sync();

  // ---------------- phase 2: kMid on blocks 0..63 --------------------------
  if (blockIdx.x < 64){
    float* WpL = (float*)pool;        // 2048
    float* T1L = WpL + 2048;          // 2048
    float* T2L = T1L + 2048;          // 2048
    float* scr = T2L + 2048;          // 2048
    float* stL = scr + 2048;          // 8
    const int t = tid, b = blockIdx.x;
    const int nb = (int)gridDim.x;

    for (int i = t; i < 2048; i += 256) WpL[i] = Wp[i];
    __syncthreads();

    {
      const float4* row = (const float4*)(Wo + t * HID);
      f32x4 a0 = z4, a1 = z4;
      #pragma unroll 8
      for (int j4 = 0; j4 < 64; ++j4){
        float4 w = row[j4];
        const f32x4* xp = (const f32x4*)&WpL[j4 * 32];
        a0 += w.x * xp[0]; a1 += w.x * xp[1];
        a0 += w.y * xp[2]; a1 += w.y * xp[3];
        a0 += w.z * xp[4]; a1 += w.z * xp[5];
        a0 += w.w * xp[6]; a1 += w.w * xp[7];
      }
      *(f32x4*)&T1L[t * 8]     = a0;
      *(f32x4*)&T1L[t * 8 + 4] = a1;
    }
    __syncthreads();

    {
      const float4* row = (const float4*)(Wv + t * HID);
      f32x4 a0 = z4, a1 = z4;
      #pragma unroll 8
      for (int j4 = 0; j4 < 64; ++j4){
        float4 w = row[j4];
        const f32x4* xp = (const f32x4*)&T1L[j4 * 32];
        a0 += w.x * xp[0]; a1 += w.x * xp[1];
        a0 += w.y * xp[2]; a1 += w.y * xp[3];
        a0 += w.z * xp[4]; a1 += w.z * xp[5];
        a0 += w.w * xp[6]; a1 += w.w * xp[7];
      }
      *(f32x4*)&T2L[t * 8]     = a0;
      *(f32x4*)&T2L[t * 8 + 4] = a1;
    }
    __syncthreads();

    {
      int cl = t >> 6, i = t & 63;
      int c = b * 4 + cl;
      float s0 = 0.f, s1 = 0.f;
      for (int b2 = i; b2 < nb; b2 += 64){
        s0 += part[b2 * 512 + c];
        s1 += part[b2 * 512 + 256 + c];
      }
      scr[cl * 128 + i]      = s0;
      scr[cl * 128 + 64 + i] = s1;
    }
    __syncthreads();
    if (t < 4){
      float s0 = 0.f, s1 = 0.f;
      for (int i = 0; i < 64; ++i){
        s0 += scr[t * 128 + i];
        s1 += scr[t * 128 + 64 + i];
      }
      const float invE = 1.0f / (float)E_CNT;
      float mu  = s0 * invE;
      float var = fmaxf(s1 * invE - mu * mu, 0.f);
      float s   = gamma[b * 4 + t] * rsqrtf(var + 4.0f * 1e-5f);
      stL[t]     = s;
      stL[4 + t] = beta[b * 4 + t] - mu * s;
    }
    __syncthreads();

    {
      int cl = t >> 6, d = (t >> 3) & 7, p8 = t & 7;
      int c = b * 4 + cl;
      const float* row = nW2 + c * HID;
      float a = 0.f;
      for (int j = p8 * 32; j < p8 * 32 + 32; ++j)
        a = fmaf(row[j], T2L[j * 8 + d], a);
      __syncthreads();
      scr[t] = a;
    }
    __syncthreads();
    {
      int cl = t >> 6, d = (t >> 3) & 7, p8 = t & 7;
      if (p8 == 0){
        float w = 0.f;
        #pragma unroll
        for (int i = 0; i < 8; ++i) w += scr[t + i];
        int c = b * 4 + cl;
        wd2t[d * HID + c]       = f2bf(0.5f * stL[cl] * w);
        wd2t[(8 + d) * HID + c] = 0;
        scr[1024 + cl * 8 + d]  = stL[4 + cl] * w;
      }
    }
    __syncthreads();
    if (t < 8){
      float a = scr[1024 + t] + scr[1024 + 8 + t] +
                scr[1024 + 16 + t] + scr[1024 + 24 + t];
      #pragma unroll
      for (int jj = 0; jj < 4; ++jj){
        int j = 4 * b + jj;
        a = fmaf(nb2[j], T2L[j * 8 + t], a);
        a = fmaf(bv[j],  T1L[j * 8 + t], a);
        a = fmaf(bo[j],  WpL[j * 8 + t], a);
      }
      if (b == 0) a += bp[t];
      atomicAdd(&bd2[t], a);
    }
  }

  cg::this_grid().sync();

  // ---------------- phase 3: k3 main pass ----------------------------------
  {
    unsigned short* hb = (unsigned short*)pool;   // 4*16*264 shorts
    const int gw = blockIdx.x * 4 + wid, ngw = gridDim.x * 4;

    short8 w2fr[8];
    #pragma unroll
    for (int kb = 0; kb < 8; ++kb)
      w2fr[kb] = *(const short8*)&wd2t[m * HID + kb * 32 + q * 8];
    const float bd2v = (m < 8) ? 0.5f * bd2[m] : 0.f;

    short8 w1fr[16];          // w1l still valid from phase 1
    #pragma unroll
    for (int nt = 0; nt < 16; ++nt)
      w1fr[nt] = *(const short8*)&w1l[(nt * 16 + m) * 24 + q * 8];

    unsigned short* myh = hb + wid * (16 * 264);

    short8 kc = {0,0,0,0,0,0,0,0};
    if (q == 2) kc[0] = (short)0x3F80;
    const bool ld  = (q < 2);
    const bool dok = (m < 8);

    int t = gw;
    short8 bcur = kc;
    if (ld && t < NTILE)
      bcur = *(const short8*)&ctxw[(size_t)t * 256 + q * 128 + m * 8];

    for (; t < NTILE; t += ngw){
      int tn = t + ngw;
      short8 bnext = kc;
      if (ld && tn < NTILE)
        bnext = *(const short8*)&ctxw[(size_t)tn * 256 + q * 128 + m * 8];

      float eav[4];
      #pragma unroll
      for (int i = 0; i < 4; ++i)
        eav[i] = dok ? ea[(t * 16 + q * 4 + i) * 8 + m] : 0.f;

      #pragma unroll
      for (int nt = 0; nt < 16; ++nt){
        f32x4 c = __builtin_amdgcn_mfma_f32_16x16x32_bf16(w1fr[nt], bcur, z4, 0, 0, 0);
        f32x4 hv = __builtin_elementwise_max(c, z4);
        *(uint2*)&myh[m * 264 + nt * 16 + q * 4] =
            make_uint2(pk_bf16(hv[0], hv[1]), pk_bf16(hv[2], hv[3]));
      }
      asm volatile("s_waitcnt lgkmcnt(0)" ::: "memory");
      f32x4 acc0 = z4, acc1 = z4;
      #pragma unroll
      for (int kb = 0; kb < 4; ++kb){
        short8 a0 = *(const short8*)&myh[m * 264 + (2*kb)   * 32 + q * 8];
        short8 a1 = *(const short8*)&myh[m * 264 + (2*kb+1) * 32 + q * 8];
        acc0 = __builtin_amdgcn_mfma_f32_16x16x32_bf16(a0, w2fr[2*kb],   acc0, 0, 0, 0);
        acc1 = __builtin_amdgcn_mfma_f32_16x16x32_bf16(a1, w2fr[2*kb+1], acc1, 0, 0, 0);
      }
      if (dok){
        #pragma unroll
        for (int i = 0; i < 4; ++i){
          float o = eav[i] + acc0[i] + acc1[i] + bd2v;
          out[(t * 16 + q * 4 + i) * 8 + m] = o;
        }
      }
      bcur = bnext;
    }
  }
}

// ===================== legacy fallback kernels (r6-proven) ==================
__global__ __launch_bounds__(256, 3) void k1_stats(
    const int* __restrict__ eidx, const float* __restrict__ nf,
    const float* __restrict__ W1, const float* __restrict__ b1,
    float* __restrict__ part, float* __restrict__ bd2,
    unsigned short* __restrict__ ctxw)
{
  __shared__ unsigned short w1l[256 * 24 + 32];
  __shared__ float sred[2][4][128];

  const int tid = threadIdx.x, lane = tid & 63, wid = tid >> 6;
  const int cg = wid & 1;
  const int pair = (blockIdx.x * 4 + wid) >> 1;
  const int npair = gridDim.x * 2;
  const int m = lane & 15, q = lane >> 4;

  if (blockIdx.x == 0 && tid < 16) bd2[tid] = 0.f;

  init_w1_lds(w1l, W1, b1, tid);
  __syncthreads();

  short8 w1fr[8];
  #pragma unroll
  for (int nt = 0; nt < 8; ++nt)
    w1fr[nt] = *(const short8*)&w1l[((cg * 8 + nt) * 16 + m) * 24 + q * 8];

  const f32x4 z4 = {0.f, 0.f, 0.f, 0.f};
  f32x4 sacc[8], qacc[8];
  #pragma unroll
  for (int nt = 0; nt < 8; ++nt){ sacc[nt] = z4; qacc[nt] = z4; }

  short8 kc = {0,0,0,0,0,0,0,0};
  if (q == 2) kc[0] = (short)0x3F80;
  const bool ld = (q < 2);

  int t = pair;
  int idc = 0;
  float4 nfa = make_float4(0.f,0.f,0.f,0.f), nfb = nfa;
  if (ld){
    int id0 = eidx[q * E_CNT + t * 16 + m];
    nfa = ((const float4*)nf)[id0 * 2];
    nfb = ((const float4*)nf)[id0 * 2 + 1];
    int tn = t + npair;
    if (tn < NTILE) idc = eidx[q * E_CNT + tn * 16 + m];
  }

  for (; t < NTILE; t += npair){
    short8 bfr = kc;
    if (ld){
      union { short8 s; uint4 u; } bu;
      bu.u = make_uint4(pk_bf16(nfa.x, nfa.y), pk_bf16(nfa.z, nfa.w),
                        pk_bf16(nfb.x, nfb.y), pk_bf16(nfb.z, nfb.w));
      bfr = bu.s;
      if (cg == 0)
        *(uint4*)&ctxw[(size_t)t * 256 + q * 128 + m * 8] = bu.u;
    }

    int tn1 = t + npair, tn2 = t + 2 * npair;
    if (ld && tn1 < NTILE){
      nfa = ((const float4*)nf)[idc * 2];
      nfb = ((const float4*)nf)[idc * 2 + 1];
      if (tn2 < NTILE) idc = eidx[q * E_CNT + tn2 * 16 + m];
    }

    #pragma unroll
    for (int nt = 0; nt < 8; ++nt){
      f32x4 c = __builtin_amdgcn_mfma_f32_16x16x32_bf16(w1fr[nt], bfr, z4, 0, 0, 0);
      f32x4 hv = __builtin_elementwise_max(c, z4);
      sacc[nt] += hv;
      qacc[nt] += hv * hv;
    }
  }

  #pragma unroll
  for (int nt = 0; nt < 8; ++nt){
    #pragma unroll
    for (int i = 0; i < 4; ++i){
      float v = sacc[nt][i], w = qacc[nt][i];
      v += __shfl_xor(v, 1); w += __shfl_xor(w, 1);
      v += __shfl_xor(v, 2); w += __shfl_xor(w, 2);
      v += __shfl_xor(v, 4); w += __shfl_xor(w, 4);
      v += __shfl_xor(v, 8); w += __shfl_xor(w, 8);
      if (m == 0){
        int loc = nt * 16 + q * 4 + i;
        sred[0][wid][loc] = v;
        sred[1][wid][loc] = w;
      }
    }
  }
  __syncthreads();
  {
    int j = tid, hf = j >> 7, loc = j & 127;
    float s0 = sred[0][hf][loc] + sred[0][hf + 2][loc];
    float s1 = sred[1][hf][loc] + sred[1][hf + 2][loc];
    part[blockIdx.x * 512 + j]       = s0;
    part[blockIdx.x * 512 + 256 + j] = s1;
  }
}

__global__ __launch_bounds__(256) void kMid(
    const float* __restrict__ part, int nb,
    const float* __restrict__ gamma, const float* __restrict__ beta,
    const float* __restrict__ nW2,
    const float* __restrict__ Wv, const float* __restrict__ Wo,
    const float* __restrict__ Wp,
    const float* __restrict__ bv, const float* __restrict__ bo,
    const float* __restrict__ bp, const float* __restrict__ nb2,
    unsigned short* __restrict__ wd2t, float* __restrict__ bd2)
{
  __shared__ float WpL[2048];
  __shared__ float T1L[2048];
  __shared__ float T2L[2048];
  __shared__ float scr[2048];
  __shared__ float stL[8];
  const int t = threadIdx.x, b = blockIdx.x;

  for (int i = t; i < 2048; i += 256) WpL[i] = Wp[i];
  __syncthreads();

  {
    const float4* row = (const float4*)(Wo + t * HID);
    f32x4 a0 = {0.f,0.f,0.f,0.f}, a1 = {0.f,0.f,0.f,0.f};
    #pragma unroll 8
    for (int j4 = 0; j4 < 64; ++j4){
      float4 w = row[j4];
      const f32x4* xp = (const f32x4*)&WpL[j4 * 32];
      a0 += w.x * xp[0]; a1 += w.x * xp[1];
      a0 += w.y * xp[2]; a1 += w.y * xp[3];
      a0 += w.z * xp[4]; a1 += w.z * xp[5];
      a0 += w.w * xp[6]; a1 += w.w * xp[7];
    }
    *(f32x4*)&T1L[t * 8]     = a0;
    *(f32x4*)&T1L[t * 8 + 4] = a1;
  }
  __syncthreads();

  {
    const float4* row = (const float4*)(Wv + t * HID);
    f32x4 a0 = {0.f,0.f,0.f,0.f}, a1 = {0.f,0.f,0.f,0.f};
    #pragma unroll 8
    for (int j4 = 0; j4 < 64; ++j4){
      float4 w = row[j4];
      const f32x4* xp = (const f32x4*)&T1L[j4 * 32];
      a0 += w.x * xp[0]; a1 += w.x * xp[1];
      a0 += w.y * xp[2]; a1 += w.y * xp[3];
      a0 += w.z * xp[4]; a1 += w.z * xp[5];
      a0 += w.w * xp[6]; a1 += w.w * xp[7];
    }
    *(f32x4*)&T2L[t * 8]     = a0;
    *(f32x4*)&T2L[t * 8 + 4] = a1;
  }
  __syncthreads();

  {
    int cl = t >> 6, i = t & 63;
    int c = b * 4 + cl;
    float s0 = 0.f, s1 = 0.f;
    for (int b2 = i; b2 < nb; b2 += 64){
      s0 += part[b2 * 512 + c];
      s1 += part[b2 * 512 + 256 + c];
    }
    scr[cl * 128 + i]      = s0;
    scr[cl * 128 + 64 + i] = s1;
  }
  __syncthreads();
  if (t < 4){
    float s0 = 0.f, s1 = 0.f;
    for (int i = 0; i < 64; ++i){
      s0 += scr[t * 128 + i];
      s1 += scr[t * 128 + 64 + i];
    }
    const float invE = 1.0f / (float)E_CNT;
    float mu  = s0 * invE;
    float var = fmaxf(s1 * invE - mu * mu, 0.f);
    float s   = gamma[b * 4 + t] * rsqrtf(var + 4.0f * 1e-5f);
    stL[t]     = s;
    stL[4 + t] = beta[b * 4 + t] - mu * s;
  }
  __syncthreads();

  {
    int cl = t >> 6, d = (t >> 3) & 7, p8 = t & 7;
    int c = b * 4 + cl;
    const float* row = nW2 + c * HID;
    float a = 0.f;
    for (int j = p8 * 32; j < p8 * 32 + 32; ++j)
      a = fmaf(row[j], T2L[j * 8 + d], a);
    scr[t] = a;
  }
  __syncthreads();
  {
    int cl = t >> 6, d = (t >> 3) & 7, p8 = t & 7;
    if (p8 == 0){
      float w = 0.f;
      #pragma unroll
      for (int i = 0; i < 8; ++i) w += scr[t + i];
      int c = b * 4 + cl;
      wd2t[d * HID + c]       = f2bf(0.5f * stL[cl] * w);
      wd2t[(8 + d) * HID + c] = 0;
      scr[1024 + cl * 8 + d]  = stL[4 + cl] * w;
    }
  }
  __syncthreads();
  if (t < 8){
    float a = scr[1024 + t] + scr[1024 + 8 + t] +
              scr[1024 + 16 + t] + scr[1024 + 24 + t];
    #pragma unroll
    for (int jj = 0; jj < 4; ++jj){
      int j = 4 * b + jj;
      a = fmaf(nb2[j], T2L[j * 8 + t], a);
      a = fmaf(bv[j],  T1L[j * 8 + t], a);
      a = fmaf(bo[j],  WpL[j * 8 + t], a);
    }
    if (b == 0) a += bp[t];
    atomicAdd(&bd2[t], a);
  }
}

__global__ __launch_bounds__(256, 3) void k3_main(
    const float* __restrict__ ea,
    const float* __restrict__ W1, const float* __restrict__ b1,
    const unsigned short* __restrict__ wd2t, const float* __restrict__ bd2,
    const unsigned short* __restrict__ ctxw,
    float* __restrict__ out)
{
  __shared__ __align__(16) unsigned short smem[4 * 16 * 264];

  const int tid = threadIdx.x, lane = tid & 63, wid = tid >> 6;
  const int gw = blockIdx.x * 4 + wid, ngw = gridDim.x * 4;
  const int m = lane & 15, q = lane >> 4;

  init_w1_lds(smem, W1, b1, tid);

  short8 w2fr[8];
  #pragma unroll
  for (int kb = 0; kb < 8; ++kb)
    w2fr[kb] = *(const short8*)&wd2t[m * HID + kb * 32 + q * 8];
  const float bd2v = (m < 8) ? 0.5f * bd2[m] : 0.f;

  __syncthreads();

  short8 w1fr[16];
  #pragma unroll
  for (int nt = 0; nt < 16; ++nt)
    w1fr[nt] = *(const short8*)&smem[(nt * 16 + m) * 24 + q * 8];

  __syncthreads();
  unsigned short* myh = smem + wid * (16 * 264);

  const f32x4 z4 = {0.f, 0.f, 0.f, 0.f};

  short8 kc = {0,0,0,0,0,0,0,0};
  if (q == 2) kc[0] = (short)0x3F80;
  const bool ld  = (q < 2);
  const bool dok = (m < 8);

  int t = gw;
  short8 bcur = kc;
  if (ld && t < NTILE)
    bcur = *(const short8*)&ctxw[(size_t)t * 256 + q * 128 + m * 8];

  for (; t < NTILE; t += ngw){
    int tn = t + ngw;
    short8 bnext = kc;
    if (ld && tn < NTILE)
      bnext = *(const short8*)&ctxw[(size_t)tn * 256 + q * 128 + m * 8];

    float eav[4];
    #pragma unroll
    for (int i = 0; i < 4; ++i)
      eav[i] = dok ? ea[(t * 16 + q * 4 + i) * 8 + m] : 0.f;

    #pragma unroll
    for (int nt = 0; nt < 16; ++nt){
      f32x4 c = __builtin_amdgcn_mfma_f32_16x16x32_bf16(w1fr[nt], bcur, z4, 0, 0, 0);
      f32x4 hv = __builtin_elementwise_max(c, z4);
      *(uint2*)&myh[m * 264 + nt * 16 + q * 4] =
          make_uint2(pk_bf16(hv[0], hv[1]), pk_bf16(hv[2], hv[3]));
    }
    asm volatile("s_waitcnt lgkmcnt(0)" ::: "memory");
    f32x4 acc0 = z4, acc1 = z4;
    #pragma unroll
    for (int kb = 0; kb < 4; ++kb){
      short8 a0 = *(const short8*)&myh[m * 264 + (2*kb)   * 32 + q * 8];
      short8 a1 = *(const short8*)&myh[m * 264 + (2*kb+1) * 32 + q * 8];
      acc0 = __builtin_amdgcn_mfma_f32_16x16x32_bf16(a0, w2fr[2*kb],   acc0, 0, 0, 0);
      acc1 = __builtin_amdgcn_mfma_f32_16x16x32_bf16(a1, w2fr[2*kb+1], acc1, 0, 0, 0);
    }
    if (dok){
      #pragma unroll
      for (int i = 0; i < 4; ++i){
        float o = eav[i] + acc0[i] + acc1[i] + bd2v;
        out[(t * 16 + q * 4 + i) * 8 + m] = o;
      }
    }
    bcur = bnext;
  }
}

extern "C" void kernel_launch(void* const* d_in, const int* in_sizes, int n_in,
                              void* d_out, int out_size, void* d_ws, size_t ws_size,
                              hipStream_t stream)
{
  const float* ea   = (const float*)d_in[0];
  const float* nf   = (const float*)d_in[1];
  const int*   eidx = (const int*)d_in[2];
  const float* nW1    = (const float*)d_in[9];
  const float* nb1    = (const float*)d_in[10];
  const float* ngamma = (const float*)d_in[11];
  const float* nbeta  = (const float*)d_in[12];
  const float* nW2    = (const float*)d_in[13];
  const float* nb2    = (const float*)d_in[14];
  const float* Wv     = (const float*)d_in[15];
  const float* bv     = (const float*)d_in[16];
  const float* Wo     = (const float*)d_in[17];
  const float* bo     = (const float*)d_in[18];
  const float* Wp     = (const float*)d_in[19];
  const float* bp     = (const float*)d_in[20];

  // ws layout (fixed offsets): [part 2MB][wd2t 8KB][bd2 64B][ctx 16MB]
  char* ws = (char*)d_ws;
  const size_t PART_BYTES = (size_t)1024 * 2048;
  float* ws_part          = (float*)(ws + 0);
  unsigned short* ws_wd2t = (unsigned short*)(ws + PART_BYTES);
  float* ws_bd2           = (float*)(ws + PART_BYTES + 8192);
  unsigned short* ws_ctx  = (unsigned short*)(ws + PART_BYTES + 8192 + 64);
  float* outp = (float*)d_out;

  // cooperative fused path: grid from occupancy query (co-residency safe)
  int maxB = 0;
  hipError_t qe = hipOccupancyMaxActiveBlocksPerMultiprocessor(&maxB, kFused, 256, 0);
  int grid = (qe == hipSuccess) ? maxB * 256 : 0;
  if (grid > 768) grid = 768;

  if (grid >= 64){
    void* args[] = {
      (void*)&eidx, (void*)&nf, (void*)&ea, (void*)&nW1, (void*)&nb1,
      (void*)&ngamma, (void*)&nbeta, (void*)&nW2,
      (void*)&Wv, (void*)&Wo, (void*)&Wp,
      (void*)&bv, (void*)&bo, (void*)&bp, (void*)&nb2,
      (void*)&ws_part, (void*)&ws_wd2t, (void*)&ws_bd2, (void*)&ws_ctx,
      (void*)&outp
    };
    hipError_t le = hipLaunchCooperativeKernel(kFused, dim3(grid), dim3(256),
                                               args, 0, stream);
    if (le == hipSuccess) return;
  }

  // legacy fallback: r6-proven 3-kernel chain
  int nb = 1024;
  k1_stats<<<dim3(nb), dim3(256), 0, stream>>>(eidx, nf, nW1, nb1,
                                               ws_part, ws_bd2, ws_ctx);
  kMid<<<dim3(64), dim3(256), 0, stream>>>(
      ws_part, nb, ngamma, nbeta, nW2, Wv, Wo, Wp, bv, bo, bp, nb2,
      ws_wd2t, ws_bd2);
  k3_main<<<dim3(1024), dim3(256), 0, stream>>>(
      ea, nW1, nb1, ws_wd2t, ws_bd2, ws_ctx, outp);
}

// Round 10
// 197.872 us; speedup vs baseline: 1.5853x; 1.5853x over previous
//
#include <hip/hip_runtime.h>
#include <hip/hip_bf16.h>
#include <string.h>

#define E_CNT 500000
#define N_CNT 100000
#define HID   256
#define NTILE 31250   // E/16

typedef short short8 __attribute__((ext_vector_type(8)));
typedef float f32x4 __attribute__((ext_vector_type(4)));

__device__ __forceinline__ unsigned short f2bf(float f){
  union { float f; unsigned int i; } v; v.f = f;
  unsigned int u = v.i;
  u = u + 0x7FFFu + ((u >> 16) & 1u);
  return (unsigned short)(u >> 16);
}

__device__ __forceinline__ unsigned int pk_bf16(float a, float b){
  __hip_bfloat162 p = __float22bfloat162_rn(make_float2(a, b));
  unsigned int u; memcpy(&u, &p, 4); return u;
}

// W1-augmented A-fragment staging. Row ch (24 shorts, 48 B):
// k0..7=W1[k][ch], k8..15=W1 again, k16=2*b1[ch], k17..23=0.
__device__ __forceinline__ void init_w1_lds(unsigned short* w1l,
                                            const float* W1, const float* b1,
                                            int tid){
  int ch = tid;
  #pragma unroll
  for (int j = 0; j < 8; ++j){
    unsigned short w = f2bf(W1[j * HID + ch]);
    w1l[ch * 24 + j]     = w;
    w1l[ch * 24 + 8 + j] = w;
  }
  w1l[ch * 24 + 16] = f2bf(2.0f * b1[ch]);
  #pragma unroll
  for (int j = 17; j < 24; ++j) w1l[ch * 24 + j] = 0;
  if (tid < 32) w1l[256 * 24 + tid] = 0;   // tail pad for q=3 of ch=255
}

// ---------------- K1: batch stats of h' = relu((nf[s]+nf[t])@W1 + 2 b1) ------
// Session-best form (197.36us total run): register-direct B-fragments, no
// LDS in the loop, 1-deep nf prefetch, 64 VGPR, (256,3).  Lessons encoded:
// r3/r8 = deeper prefetch or tighter launch_bounds crosses the 64-VGPR
// granule -> spill/occupancy cliff.  r5/r7 = grid scaling is neutral; k1's
// ~43us appears floor'd by concurrent harness reset fills (dur invariant
// across all structural variants, pipes all <50%).
__global__ __launch_bounds__(256, 3) void k1_stats(
    const int* __restrict__ eidx, const float* __restrict__ nf,
    const float* __restrict__ W1, const float* __restrict__ b1,
    float* __restrict__ part, float* __restrict__ bd2,
    unsigned short* __restrict__ ctxw)
{
  __shared__ unsigned short w1l[256 * 24 + 32];
  __shared__ float sred[2][4][128];

  const int tid = threadIdx.x, lane = tid & 63, wid = tid >> 6;
  const int cg = wid & 1;                         // channel group
  const int pair = (blockIdx.x * 4 + wid) >> 1;   // edge-tile stream
  const int npair = gridDim.x * 2;
  const int m = lane & 15, q = lane >> 4;

  if (blockIdx.x == 0 && tid < 16) bd2[tid] = 0.f;   // kMid atomicAdds later

  init_w1_lds(w1l, W1, b1, tid);
  __syncthreads();

  short8 w1fr[8];                  // hoisted once; 32 VGPRs
  #pragma unroll
  for (int nt = 0; nt < 8; ++nt)
    w1fr[nt] = *(const short8*)&w1l[((cg * 8 + nt) * 16 + m) * 24 + q * 8];

  const f32x4 z4 = {0.f, 0.f, 0.f, 0.f};
  f32x4 sacc[8], qacc[8];
  #pragma unroll
  for (int nt = 0; nt < 8; ++nt){ sacc[nt] = z4; qacc[nt] = z4; }

  // constant fragment for q>=2 (k=16 bias column / zero pad)
  short8 kc = {0,0,0,0,0,0,0,0};
  if (q == 2) kc[0] = (short)0x3F80;
  const bool ld = (q < 2);

  int t = pair;
  int idc = 0;
  float4 nfa = make_float4(0.f,0.f,0.f,0.f), nfb = nfa;
  if (ld){                                     // rows for first tile
    int id0 = eidx[q * E_CNT + t * 16 + m];
    nfa = ((const float4*)nf)[id0 * 2];
    nfb = ((const float4*)nf)[id0 * 2 + 1];
    int tn = t + npair;
    if (tn < NTILE) idc = eidx[q * E_CNT + tn * 16 + m];
  }

  for (; t < NTILE; t += npair){
    short8 bfr = kc;
    if (ld){
      union { short8 s; uint4 u; } bu;
      bu.u = make_uint4(pk_bf16(nfa.x, nfa.y), pk_bf16(nfa.z, nfa.w),
                        pk_bf16(nfb.x, nfb.y), pk_bf16(nfb.z, nfb.w));
      bfr = bu.s;
      if (cg == 0)   // persist packed tile for k3 (16B/lane, q-major layout)
        *(uint4*)&ctxw[(size_t)t * 256 + q * 128 + m * 8] = bu.u;
    }

    int tn1 = t + npair, tn2 = t + 2 * npair;
    if (ld && tn1 < NTILE){                    // prefetch rows for t+1
      nfa = ((const float4*)nf)[idc * 2];
      nfb = ((const float4*)nf)[idc * 2 + 1];
      if (tn2 < NTILE) idc = eidx[q * E_CNT + tn2 * 16 + m];
    }

    #pragma unroll
    for (int nt = 0; nt < 8; ++nt){
      f32x4 c = __builtin_amdgcn_mfma_f32_16x16x32_bf16(w1fr[nt], bfr, z4, 0, 0, 0);
      f32x4 hv = __builtin_elementwise_max(c, z4);
      sacc[nt] += hv;
      qacc[nt] += hv * hv;
    }
  }

  #pragma unroll
  for (int nt = 0; nt < 8; ++nt){
    #pragma unroll
    for (int i = 0; i < 4; ++i){
      float v = sacc[nt][i], w = qacc[nt][i];
      v += __shfl_xor(v, 1); w += __shfl_xor(w, 1);
      v += __shfl_xor(v, 2); w += __shfl_xor(w, 2);
      v += __shfl_xor(v, 4); w += __shfl_xor(w, 4);
      v += __shfl_xor(v, 8); w += __shfl_xor(w, 8);
      if (m == 0){
        int loc = nt * 16 + q * 4 + i;   // 0..127 within channel group
        sred[0][wid][loc] = v;
        sred[1][wid][loc] = w;
      }
    }
  }
  __syncthreads();
  {
    int j = tid, hf = j >> 7, loc = j & 127;
    float s0 = sred[0][hf][loc] + sred[0][hf + 2][loc];
    float s1 = sred[1][hf][loc] + sred[1][hf + 2][loc];
    part[blockIdx.x * 512 + j]       = s0;
    part[blockIdx.x * 512 + 256 + j] = s1;
  }
}

// ---------------- kMid: T1/T2 small matmuls + stats-fold + Wd rows + bias ----
__global__ __launch_bounds__(256) void kMid(
    const float* __restrict__ part, int nb,
    const float* __restrict__ gamma, const float* __restrict__ beta,
    const float* __restrict__ nW2,
    const float* __restrict__ Wv, const float* __restrict__ Wo,
    const float* __restrict__ Wp,
    const float* __restrict__ bv, const float* __restrict__ bo,
    const float* __restrict__ bp, const float* __restrict__ nb2,
    unsigned short* __restrict__ wd2t, float* __restrict__ bd2)
{
  __shared__ float WpL[2048];   // Wp [256][8]
  __shared__ float T1L[2048];   // T1 = Wo@Wp
  __shared__ float T2L[2048];   // T2 = Wv@T1
  __shared__ float scr[2048];
  __shared__ float stL[8];
  const int t = threadIdx.x, b = blockIdx.x;

  for (int i = t; i < 2048; i += 256) WpL[i] = Wp[i];
  __syncthreads();

  // T1 row t = Wo[t][:] @ WpL
  {
    const float4* row = (const float4*)(Wo + t * HID);
    f32x4 a0 = {0.f,0.f,0.f,0.f}, a1 = {0.f,0.f,0.f,0.f};
    #pragma unroll 8
    for (int j4 = 0; j4 < 64; ++j4){
      float4 w = row[j4];
      const f32x4* xp = (const f32x4*)&WpL[j4 * 32];
      a0 += w.x * xp[0]; a1 += w.x * xp[1];
      a0 += w.y * xp[2]; a1 += w.y * xp[3];
      a0 += w.z * xp[4]; a1 += w.z * xp[5];
      a0 += w.w * xp[6]; a1 += w.w * xp[7];
    }
    *(f32x4*)&T1L[t * 8]     = a0;
    *(f32x4*)&T1L[t * 8 + 4] = a1;
  }
  __syncthreads();

  // T2 row t = Wv[t][:] @ T1L
  {
    const float4* row = (const float4*)(Wv + t * HID);
    f32x4 a0 = {0.f,0.f,0.f,0.f}, a1 = {0.f,0.f,0.f,0.f};
    #pragma unroll 8
    for (int j4 = 0; j4 < 64; ++j4){
      float4 w = row[j4];
      const f32x4* xp = (const f32x4*)&T1L[j4 * 32];
      a0 += w.x * xp[0]; a1 += w.x * xp[1];
      a0 += w.y * xp[2]; a1 += w.y * xp[3];
      a0 += w.z * xp[4]; a1 += w.z * xp[5];
      a0 += w.w * xp[6]; a1 += w.w * xp[7];
    }
    *(f32x4*)&T2L[t * 8]     = a0;
    *(f32x4*)&T2L[t * 8 + 4] = a1;
  }
  __syncthreads();

  // ---- former kC body ----
  {
    int cl = t >> 6, i = t & 63;
    int c = b * 4 + cl;
    float s0 = 0.f, s1 = 0.f;
    for (int b2 = i; b2 < nb; b2 += 64){
      s0 += part[b2 * 512 + c];
      s1 += part[b2 * 512 + 256 + c];
    }
    scr[cl * 128 + i]      = s0;
    scr[cl * 128 + 64 + i] = s1;
  }
  __syncthreads();
  if (t < 4){
    float s0 = 0.f, s1 = 0.f;
    for (int i = 0; i < 64; ++i){
      s0 += scr[t * 128 + i];
      s1 += scr[t * 128 + 64 + i];
    }
    const float invE = 1.0f / (float)E_CNT;
    float mu  = s0 * invE;
    float var = fmaxf(s1 * invE - mu * mu, 0.f);
    float s   = gamma[b * 4 + t] * rsqrtf(var + 4.0f * 1e-5f);  // eps' = 4*eps
    stL[t]     = s;
    stL[4 + t] = beta[b * 4 + t] - mu * s;
  }
  __syncthreads();

  {
    int cl = t >> 6, d = (t >> 3) & 7, p8 = t & 7;
    int c = b * 4 + cl;
    const float* row = nW2 + c * HID;
    float a = 0.f;
    for (int j = p8 * 32; j < p8 * 32 + 32; ++j)
      a = fmaf(row[j], T2L[j * 8 + d], a);
    scr[t] = a;
  }
  __syncthreads();
  {
    int cl = t >> 6, d = (t >> 3) & 7, p8 = t & 7;
    if (p8 == 0){
      float w = 0.f;
      #pragma unroll
      for (int i = 0; i < 8; ++i) w += scr[t + i];
      int c = b * 4 + cl;
      wd2t[d * HID + c]       = f2bf(0.5f * stL[cl] * w);
      wd2t[(8 + d) * HID + c] = 0;                 // pad rows d=8..15
      scr[1024 + cl * 8 + d]  = stL[4 + cl] * w;   // tt*Wd contribution
    }
  }
  __syncthreads();
  if (t < 8){
    float a = scr[1024 + t] + scr[1024 + 8 + t] +
              scr[1024 + 16 + t] + scr[1024 + 24 + t];
    #pragma unroll
    for (int jj = 0; jj < 4; ++jj){     // static chain, j-slice of this block
      int j = 4 * b + jj;
      a = fmaf(nb2[j], T2L[j * 8 + t], a);
      a = fmaf(bv[j],  T1L[j * 8 + t], a);
      a = fmaf(bo[j],  WpL[j * 8 + t], a);
    }
    if (b == 0) a += bp[t];
    atomicAdd(&bd2[t], a);
  }
}

// ---------------- K3: out = edge_attr + h' @ Wd2 + bd2 ----------------------
// Session-best form: LDS overlay (w1l dead after fragment hoist -> hbuf
// reuses it, 33.8KB), explicit lgkmcnt drain between mm1 and mm2, q-major
// ctxw prefetched one tile ahead, two independent mm2 MFMA chains.
__global__ __launch_bounds__(256, 3) void k3_main(
    const float* __restrict__ ea,
    const float* __restrict__ W1, const float* __restrict__ b1,
    const unsigned short* __restrict__ wd2t, const float* __restrict__ bd2,
    const unsigned short* __restrict__ ctxw,
    float* __restrict__ out)
{
  __shared__ __align__(16) unsigned short smem[4 * 16 * 264];  // 33792 B

  const int tid = threadIdx.x, lane = tid & 63, wid = tid >> 6;
  const int gw = blockIdx.x * 4 + wid, ngw = gridDim.x * 4;
  const int m = lane & 15, q = lane >> 4;

  init_w1_lds(smem, W1, b1, tid);   // smem serves as w1l (6208 < 16896 shorts)

  short8 w2fr[8];
  #pragma unroll
  for (int kb = 0; kb < 8; ++kb)
    w2fr[kb] = *(const short8*)&wd2t[m * HID + kb * 32 + q * 8];
  const float bd2v = (m < 8) ? 0.5f * bd2[m] : 0.f;

  __syncthreads();

  short8 w1fr[16];                 // hoisted from the w1l staging
  #pragma unroll
  for (int nt = 0; nt < 16; ++nt)
    w1fr[nt] = *(const short8*)&smem[(nt * 16 + m) * 24 + q * 8];

  __syncthreads();                 // w1l dead; smem becomes hbuf
  unsigned short* myh = smem + wid * (16 * 264);

  const f32x4 z4 = {0.f, 0.f, 0.f, 0.f};

  // constant B-fragment for q>=2 lanes (k=16 bias column / zero pad)
  short8 kc = {0,0,0,0,0,0,0,0};
  if (q == 2) kc[0] = (short)0x3F80;
  const bool ld  = (q < 2);
  const bool dok = (m < 8);

  int t = gw;
  short8 bcur = kc;
  if (ld && t < NTILE)
    bcur = *(const short8*)&ctxw[(size_t)t * 256 + q * 128 + m * 8];

  for (; t < NTILE; t += ngw){
    int tn = t + ngw;
    short8 bnext = kc;
    if (ld && tn < NTILE)
      bnext = *(const short8*)&ctxw[(size_t)tn * 256 + q * 128 + m * 8];

    float eav[4];
    #pragma unroll
    for (int i = 0; i < 4; ++i)
      eav[i] = dok ? ea[(t * 16 + q * 4 + i) * 8 + m] : 0.f;

    // mm1: h' tile -> packed bf16 -> LDS (j-contiguous per lane)
    #pragma unroll
    for (int nt = 0; nt < 16; ++nt){
      f32x4 c = __builtin_amdgcn_mfma_f32_16x16x32_bf16(w1fr[nt], bcur, z4, 0, 0, 0);
      f32x4 hv = __builtin_elementwise_max(c, z4);
      *(uint2*)&myh[m * 264 + nt * 16 + q * 4] =
          make_uint2(pk_bf16(hv[0], hv[1]), pk_bf16(hv[2], hv[3]));
    }
    asm volatile("s_waitcnt lgkmcnt(0)" ::: "memory");
    // mm2: out tile = h' @ Wd2 — two independent accumulation chains
    f32x4 acc0 = z4, acc1 = z4;
    #pragma unroll
    for (int kb = 0; kb < 4; ++kb){
      short8 a0 = *(const short8*)&myh[m * 264 + (2*kb)   * 32 + q * 8];
      short8 a1 = *(const short8*)&myh[m * 264 + (2*kb+1) * 32 + q * 8];
      acc0 = __builtin_amdgcn_mfma_f32_16x16x32_bf16(a0, w2fr[2*kb],   acc0, 0, 0, 0);
      acc1 = __builtin_amdgcn_mfma_f32_16x16x32_bf16(a1, w2fr[2*kb+1], acc1, 0, 0, 0);
    }
    if (dok){
      #pragma unroll
      for (int i = 0; i < 4; ++i){
        float o = eav[i] + acc0[i] + acc1[i] + bd2v;
        out[(t * 16 + q * 4 + i) * 8 + m] = o;
      }
    }
    bcur = bnext;
  }
}

extern "C" void kernel_launch(void* const* d_in, const int* in_sizes, int n_in,
                              void* d_out, int out_size, void* d_ws, size_t ws_size,
                              hipStream_t stream)
{
  const float* ea   = (const float*)d_in[0];
  const float* nf   = (const float*)d_in[1];
  const int*   eidx = (const int*)d_in[2];
  // d_in[3..8] = edge-encoder params: dead code in the reference.
  const float* nW1    = (const float*)d_in[9];
  const float* nb1    = (const float*)d_in[10];
  const float* ngamma = (const float*)d_in[11];
  const float* nbeta  = (const float*)d_in[12];
  const float* nW2    = (const float*)d_in[13];
  const float* nb2    = (const float*)d_in[14];
  const float* Wv     = (const float*)d_in[15];
  const float* bv     = (const float*)d_in[16];
  const float* Wo     = (const float*)d_in[17];
  const float* bo     = (const float*)d_in[18];
  const float* Wp     = (const float*)d_in[19];
  const float* bp     = (const float*)d_in[20];

  // ws layout: [nb*512 f32 part][wd2t 16x256 bf16][bd2 16 f32][ctx 16 MB]
  const size_t CTX_BYTES = (size_t)NTILE * 512;   // packed bf16 ctx tiles
  long avail = (long)ws_size - 8192 - 64 - (long)CTX_BYTES - 1024;
  int nb = (int)(avail / 2048);
  if (nb > 1024) nb = 1024;
  if (nb < 1)    nb = 1;

  char* ws = (char*)d_ws;
  size_t off = (size_t)nb * 2048;
  float* ws_part          = (float*)(ws + 0);
  unsigned short* ws_wd2t = (unsigned short*)(ws + off);
  float* ws_bd2           = (float*)(ws + off + 8192);
  unsigned short* ws_ctx  = (unsigned short*)(ws + off + 8192 + 64);

  k1_stats<<<dim3(nb), dim3(256), 0, stream>>>(eidx, nf, nW1, nb1,
                                               ws_part, ws_bd2, ws_ctx);
  kMid<<<dim3(64), dim3(256), 0, stream>>>(
      ws_part, nb, ngamma, nbeta, nW2, Wv, Wo, Wp, bv, bo, bp, nb2,
      ws_wd2t, ws_bd2);
  k3_main<<<dim3(1024), dim3(256), 0, stream>>>(
      ea, nW1, nb1, ws_wd2t, ws_bd2, ws_ctx, (float*)d_out);
}

// Round 12
// 196.035 us; speedup vs baseline: 1.6002x; 1.0094x over previous
//
#include <hip/hip_runtime.h>
#include <hip/hip_bf16.h>
#include <string.h>

#define E_CNT 500000
#define N_CNT 100000
#define HID   256
#define NTILE 31250   // E/16

typedef short short8 __attribute__((ext_vector_type(8)));
typedef float f32x4 __attribute__((ext_vector_type(4)));

__device__ __forceinline__ unsigned short f2bf(float f){
  union { float f; unsigned int i; } v; v.f = f;
  unsigned int u = v.i;
  u = u + 0x7FFFu + ((u >> 16) & 1u);
  return (unsigned short)(u >> 16);
}

__device__ __forceinline__ unsigned int pk_bf16(float a, float b){
  __hip_bfloat162 p = __float22bfloat162_rn(make_float2(a, b));
  unsigned int u; memcpy(&u, &p, 4); return u;
}

// W1-augmented A-fragment staging. Row ch (24 shorts, 48 B):
// k0..7=W1[k][ch], k8..15=W1 again, k16=2*b1[ch], k17..23=0.
__device__ __forceinline__ void init_w1_lds(unsigned short* w1l,
                                            const float* W1, const float* b1,
                                            int tid){
  int ch = tid;
  #pragma unroll
  for (int j = 0; j < 8; ++j){
    unsigned short w = f2bf(W1[j * HID + ch]);
    w1l[ch * 24 + j]     = w;
    w1l[ch * 24 + 8 + j] = w;
  }
  w1l[ch * 24 + 16] = f2bf(2.0f * b1[ch]);
  #pragma unroll
  for (int j = 17; j < 24; ++j) w1l[ch * 24 + j] = 0;
  if (tid < 32) w1l[256 * 24 + tid] = 0;   // tail pad for q=3 of ch=255
}

// ---------------- K1: batch stats of h' = relu((nf[s]+nf[t])@W1 + 2 b1) ------
// r10 theory: r6-form used 64 VGPR + 64 AGPR = 128 unified regs/wave = exactly
// the 4-waves/SIMD bracket boundary; latency-bound there (VALUBusy 37%), and
// every register ADDITION regressed (r8: 136 regs -> occ 20.8%).  This round
// goes the other way: 4-way channel split.  Each of the 4 waves covers 64
// channels of the SAME tile stream: w1fr[4]=16 VGPR, sacc/qacc[4]=32 AGPR,
// ~90-96 unified total -> more waves/SIMD + halved per-iteration dep chain.
// Gather is 4x-duplicated across the block's waves but sibling accesses are
// L1 hits.  Channels are wave-exclusive -> reduction needs no cross-wave add.
__global__ __launch_bounds__(256, 3) void k1_stats(
    const int* __restrict__ eidx, const float* __restrict__ nf,
    const float* __restrict__ W1, const float* __restrict__ b1,
    float* __restrict__ part, float* __restrict__ bd2,
    unsigned short* __restrict__ ctxw)
{
  __shared__ unsigned short w1l[256 * 24 + 32];
  __shared__ float sred[2][4][64];

  const int tid = threadIdx.x, lane = tid & 63, wid = tid >> 6;
  const int cg = wid;                             // channel group 0..3 (64 ch)
  const int m = lane & 15, q = lane >> 4;

  if (blockIdx.x == 0 && tid < 16) bd2[tid] = 0.f;   // kMid atomicAdds later

  init_w1_lds(w1l, W1, b1, tid);
  __syncthreads();

  short8 w1fr[4];                  // hoisted once; 16 VGPRs
  #pragma unroll
  for (int nt = 0; nt < 4; ++nt)
    w1fr[nt] = *(const short8*)&w1l[((cg * 4 + nt) * 16 + m) * 24 + q * 8];

  const f32x4 z4 = {0.f, 0.f, 0.f, 0.f};
  f32x4 sacc[4], qacc[4];          // 32 AGPRs
  #pragma unroll
  for (int nt = 0; nt < 4; ++nt){ sacc[nt] = z4; qacc[nt] = z4; }

  // constant fragment for q>=2 (k=16 bias column / zero pad)
  short8 kc = {0,0,0,0,0,0,0,0};
  if (q == 2) kc[0] = (short)0x3F80;
  const bool ld = (q < 2);

  const int stride = gridDim.x;
  int t = blockIdx.x;
  int idc = 0;
  float4 nfa = make_float4(0.f,0.f,0.f,0.f), nfb = nfa;
  if (ld){                                     // rows for first tile
    int id0 = eidx[q * E_CNT + t * 16 + m];
    nfa = ((const float4*)nf)[id0 * 2];
    nfb = ((const float4*)nf)[id0 * 2 + 1];
    int tn = t + stride;
    if (tn < NTILE) idc = eidx[q * E_CNT + tn * 16 + m];
  }

  for (; t < NTILE; t += stride){
    short8 bfr = kc;
    if (ld){
      union { short8 s; uint4 u; } bu;
      bu.u = make_uint4(pk_bf16(nfa.x, nfa.y), pk_bf16(nfa.z, nfa.w),
                        pk_bf16(nfb.x, nfb.y), pk_bf16(nfb.z, nfb.w));
      bfr = bu.s;
      if (cg == 0)   // persist packed tile for k3 (16B/lane, q-major layout)
        *(uint4*)&ctxw[(size_t)t * 256 + q * 128 + m * 8] = bu.u;
    }

    int tn1 = t + stride, tn2 = t + 2 * stride;
    if (ld && tn1 < NTILE){                    // prefetch rows for t+1
      nfa = ((const float4*)nf)[idc * 2];
      nfb = ((const float4*)nf)[idc * 2 + 1];
      if (tn2 < NTILE) idc = eidx[q * E_CNT + tn2 * 16 + m];
    }

    #pragma unroll
    for (int nt = 0; nt < 4; ++nt){
      f32x4 c = __builtin_amdgcn_mfma_f32_16x16x32_bf16(w1fr[nt], bfr, z4, 0, 0, 0);
      f32x4 hv = __builtin_elementwise_max(c, z4);
      sacc[nt] += hv;
      qacc[nt] += hv * hv;
    }
  }

  #pragma unroll
  for (int nt = 0; nt < 4; ++nt){
    #pragma unroll
    for (int i = 0; i < 4; ++i){
      float v = sacc[nt][i], w = qacc[nt][i];
      v += __shfl_xor(v, 1); w += __shfl_xor(w, 1);
      v += __shfl_xor(v, 2); w += __shfl_xor(w, 2);
      v += __shfl_xor(v, 4); w += __shfl_xor(w, 4);
      v += __shfl_xor(v, 8); w += __shfl_xor(w, 8);
      if (m == 0){
        int loc = nt * 16 + q * 4 + i;   // 0..63 within channel group
        sred[0][cg][loc] = v;
        sred[1][cg][loc] = w;
      }
    }
  }
  __syncthreads();
  {
    int j = tid, g = j >> 6, loc = j & 63;   // channel j owned by wave g
    part[blockIdx.x * 512 + j]       = sred[0][g][loc];
    part[blockIdx.x * 512 + 256 + j] = sred[1][g][loc];
  }
}

// ---------------- kMid: T1/T2 small matmuls + stats-fold + Wd rows + bias ----
__global__ __launch_bounds__(256) void kMid(
    const float* __restrict__ part, int nb,
    const float* __restrict__ gamma, const float* __restrict__ beta,
    const float* __restrict__ nW2,
    const float* __restrict__ Wv, const float* __restrict__ Wo,
    const float* __restrict__ Wp,
    const float* __restrict__ bv, const float* __restrict__ bo,
    const float* __restrict__ bp, const float* __restrict__ nb2,
    unsigned short* __restrict__ wd2t, float* __restrict__ bd2)
{
  __shared__ float WpL[2048];   // Wp [256][8]
  __shared__ float T1L[2048];   // T1 = Wo@Wp
  __shared__ float T2L[2048];   // T2 = Wv@T1
  __shared__ float scr[2048];
  __shared__ float stL[8];
  const int t = threadIdx.x, b = blockIdx.x;

  for (int i = t; i < 2048; i += 256) WpL[i] = Wp[i];
  __syncthreads();

  // T1 row t = Wo[t][:] @ WpL
  {
    const float4* row = (const float4*)(Wo + t * HID);
    f32x4 a0 = {0.f,0.f,0.f,0.f}, a1 = {0.f,0.f,0.f,0.f};
    #pragma unroll 8
    for (int j4 = 0; j4 < 64; ++j4){
      float4 w = row[j4];
      const f32x4* xp = (const f32x4*)&WpL[j4 * 32];
      a0 += w.x * xp[0]; a1 += w.x * xp[1];
      a0 += w.y * xp[2]; a1 += w.y * xp[3];
      a0 += w.z * xp[4]; a1 += w.z * xp[5];
      a0 += w.w * xp[6]; a1 += w.w * xp[7];
    }
    *(f32x4*)&T1L[t * 8]     = a0;
    *(f32x4*)&T1L[t * 8 + 4] = a1;
  }
  __syncthreads();

  // T2 row t = Wv[t][:] @ T1L
  {
    const float4* row = (const float4*)(Wv + t * HID);
    f32x4 a0 = {0.f,0.f,0.f,0.f}, a1 = {0.f,0.f,0.f,0.f};
    #pragma unroll 8
    for (int j4 = 0; j4 < 64; ++j4){
      float4 w = row[j4];
      const f32x4* xp = (const f32x4*)&T1L[j4 * 32];
      a0 += w.x * xp[0]; a1 += w.x * xp[1];
      a0 += w.y * xp[2]; a1 += w.y * xp[3];
      a0 += w.z * xp[4]; a1 += w.z * xp[5];
      a0 += w.w * xp[6]; a1 += w.w * xp[7];
    }
    *(f32x4*)&T2L[t * 8]     = a0;
    *(f32x4*)&T2L[t * 8 + 4] = a1;
  }
  __syncthreads();

  // ---- former kC body ----
  {
    int cl = t >> 6, i = t & 63;
    int c = b * 4 + cl;
    float s0 = 0.f, s1 = 0.f;
    for (int b2 = i; b2 < nb; b2 += 64){
      s0 += part[b2 * 512 + c];
      s1 += part[b2 * 512 + 256 + c];
    }
    scr[cl * 128 + i]      = s0;
    scr[cl * 128 + 64 + i] = s1;
  }
  __syncthreads();
  if (t < 4){
    float s0 = 0.f, s1 = 0.f;
    for (int i = 0; i < 64; ++i){
      s0 += scr[t * 128 + i];
      s1 += scr[t * 128 + 64 + i];
    }
    const float invE = 1.0f / (float)E_CNT;
    float mu  = s0 * invE;
    float var = fmaxf(s1 * invE - mu * mu, 0.f);
    float s   = gamma[b * 4 + t] * rsqrtf(var + 4.0f * 1e-5f);  // eps' = 4*eps
    stL[t]     = s;
    stL[4 + t] = beta[b * 4 + t] - mu * s;
  }
  __syncthreads();

  {
    int cl = t >> 6, d = (t >> 3) & 7, p8 = t & 7;
    int c = b * 4 + cl;
    const float* row = nW2 + c * HID;
    float a = 0.f;
    for (int j = p8 * 32; j < p8 * 32 + 32; ++j)
      a = fmaf(row[j], T2L[j * 8 + d], a);
    scr[t] = a;
  }
  __syncthreads();
  {
    int cl = t >> 6, d = (t >> 3) & 7, p8 = t & 7;
    if (p8 == 0){
      float w = 0.f;
      #pragma unroll
      for (int i = 0; i < 8; ++i) w += scr[t + i];
      int c = b * 4 + cl;
      wd2t[d * HID + c]       = f2bf(0.5f * stL[cl] * w);
      wd2t[(8 + d) * HID + c] = 0;                 // pad rows d=8..15
      scr[1024 + cl * 8 + d]  = stL[4 + cl] * w;   // tt*Wd contribution
    }
  }
  __syncthreads();
  if (t < 8){
    float a = scr[1024 + t] + scr[1024 + 8 + t] +
              scr[1024 + 16 + t] + scr[1024 + 24 + t];
    #pragma unroll
    for (int jj = 0; jj < 4; ++jj){     // static chain, j-slice of this block
      int j = 4 * b + jj;
      a = fmaf(nb2[j], T2L[j * 8 + t], a);
      a = fmaf(bv[j],  T1L[j * 8 + t], a);
      a = fmaf(bo[j],  WpL[j * 8 + t], a);
    }
    if (b == 0) a += bp[t];
    atomicAdd(&bd2[t], a);
  }
}

// ---------------- K3: out = edge_attr + h' @ Wd2 + bd2 ----------------------
// Session-best form: LDS overlay (w1l dead after fragment hoist -> hbuf
// reuses it, 33.8KB), explicit lgkmcnt drain between mm1 and mm2, q-major
// ctxw prefetched one tile ahead, two independent mm2 MFMA chains.
__global__ __launch_bounds__(256, 3) void k3_main(
    const float* __restrict__ ea,
    const float* __restrict__ W1, const float* __restrict__ b1,
    const unsigned short* __restrict__ wd2t, const float* __restrict__ bd2,
    const unsigned short* __restrict__ ctxw,
    float* __restrict__ out)
{
  __shared__ __align__(16) unsigned short smem[4 * 16 * 264];  // 33792 B

  const int tid = threadIdx.x, lane = tid & 63, wid = tid >> 6;
  const int gw = blockIdx.x * 4 + wid, ngw = gridDim.x * 4;
  const int m = lane & 15, q = lane >> 4;

  init_w1_lds(smem, W1, b1, tid);   // smem serves as w1l (6208 < 16896 shorts)

  short8 w2fr[8];
  #pragma unroll
  for (int kb = 0; kb < 8; ++kb)
    w2fr[kb] = *(const short8*)&wd2t[m * HID + kb * 32 + q * 8];
  const float bd2v = (m < 8) ? 0.5f * bd2[m] : 0.f;

  __syncthreads();

  short8 w1fr[16];                 // hoisted from the w1l staging
  #pragma unroll
  for (int nt = 0; nt < 16; ++nt)
    w1fr[nt] = *(const short8*)&smem[(nt * 16 + m) * 24 + q * 8];

  __syncthreads();                 // w1l dead; smem becomes hbuf
  unsigned short* myh = smem + wid * (16 * 264);

  const f32x4 z4 = {0.f, 0.f, 0.f, 0.f};

  // constant B-fragment for q>=2 lanes (k=16 bias column / zero pad)
  short8 kc = {0,0,0,0,0,0,0,0};
  if (q == 2) kc[0] = (short)0x3F80;
  const bool ld  = (q < 2);
  const bool dok = (m < 8);

  int t = gw;
  short8 bcur = kc;
  if (ld && t < NTILE)
    bcur = *(const short8*)&ctxw[(size_t)t * 256 + q * 128 + m * 8];

  for (; t < NTILE; t += ngw){
    int tn = t + ngw;
    short8 bnext = kc;
    if (ld && tn < NTILE)
      bnext = *(const short8*)&ctxw[(size_t)tn * 256 + q * 128 + m * 8];

    float eav[4];
    #pragma unroll
    for (int i = 0; i < 4; ++i)
      eav[i] = dok ? ea[(t * 16 + q * 4 + i) * 8 + m] : 0.f;

    // mm1: h' tile -> packed bf16 -> LDS (j-contiguous per lane)
    #pragma unroll
    for (int nt = 0; nt < 16; ++nt){
      f32x4 c = __builtin_amdgcn_mfma_f32_16x16x32_bf16(w1fr[nt], bcur, z4, 0, 0, 0);
      f32x4 hv = __builtin_elementwise_max(c, z4);
      *(uint2*)&myh[m * 264 + nt * 16 + q * 4] =
          make_uint2(pk_bf16(hv[0], hv[1]), pk_bf16(hv[2], hv[3]));
    }
    asm volatile("s_waitcnt lgkmcnt(0)" ::: "memory");
    // mm2: out tile = h' @ Wd2 — two independent accumulation chains
    f32x4 acc0 = z4, acc1 = z4;
    #pragma unroll
    for (int kb = 0; kb < 4; ++kb){
      short8 a0 = *(const short8*)&myh[m * 264 + (2*kb)   * 32 + q * 8];
      short8 a1 = *(const short8*)&myh[m * 264 + (2*kb+1) * 32 + q * 8];
      acc0 = __builtin_amdgcn_mfma_f32_16x16x32_bf16(a0, w2fr[2*kb],   acc0, 0, 0, 0);
      acc1 = __builtin_amdgcn_mfma_f32_16x16x32_bf16(a1, w2fr[2*kb+1], acc1, 0, 0, 0);
    }
    if (dok){
      #pragma unroll
      for (int i = 0; i < 4; ++i){
        float o = eav[i] + acc0[i] + acc1[i] + bd2v;
        out[(t * 16 + q * 4 + i) * 8 + m] = o;
      }
    }
    bcur = bnext;
  }
}

extern "C" void kernel_launch(void* const* d_in, const int* in_sizes, int n_in,
                              void* d_out, int out_size, void* d_ws, size_t ws_size,
                              hipStream_t stream)
{
  const float* ea   = (const float*)d_in[0];
  const float* nf   = (const float*)d_in[1];
  const int*   eidx = (const int*)d_in[2];
  // d_in[3..8] = edge-encoder params: dead code in the reference.
  const float* nW1    = (const float*)d_in[9];
  const float* nb1    = (const float*)d_in[10];
  const float* ngamma = (const float*)d_in[11];
  const float* nbeta  = (const float*)d_in[12];
  const float* nW2    = (const float*)d_in[13];
  const float* nb2    = (const float*)d_in[14];
  const float* Wv     = (const float*)d_in[15];
  const float* bv     = (const float*)d_in[16];
  const float* Wo     = (const float*)d_in[17];
  const float* bo     = (const float*)d_in[18];
  const float* Wp     = (const float*)d_in[19];
  const float* bp     = (const float*)d_in[20];

  // ws layout: [nb*512 f32 part][wd2t 16x256 bf16][bd2 16 f32][ctx 16 MB]
  const size_t CTX_BYTES = (size_t)NTILE * 512;   // packed bf16 ctx tiles
  long avail = (long)ws_size - 8192 - 64 - (long)CTX_BYTES - 1024;
  int nb = (int)(avail / 2048);
  if (nb > 1024) nb = 1024;
  if (nb < 1)    nb = 1;

  char* ws = (char*)d_ws;
  size_t off = (size_t)nb * 2048;
  float* ws_part          = (float*)(ws + 0);
  unsigned short* ws_wd2t = (unsigned short*)(ws + off);
  float* ws_bd2           = (float*)(ws + off + 8192);
  unsigned short* ws_ctx  = (unsigned short*)(ws + off + 8192 + 64);

  k1_stats<<<dim3(nb), dim3(256), 0, stream>>>(eidx, nf, nW1, nb1,
                                               ws_part, ws_bd2, ws_ctx);
  kMid<<<dim3(64), dim3(256), 0, stream>>>(
      ws_part, nb, ngamma, nbeta, nW2, Wv, Wo, Wp, bv, bo, bp, nb2,
      ws_wd2t, ws_bd2);
  k3_main<<<dim3(1024), dim3(256), 0, stream>>>(
      ea, nW1, nb1, ws_wd2t, ws_bd2, ws_ctx, (float*)d_out);
}